// Round 5
// baseline (77.101 us; speedup 1.0000x reference)
//
#include <hip/hip_runtime.h>

#define MDIM 4096
#define NDIM 4096
#define NCOEF 768
#define ALPHA 16.0f

typedef __attribute__((ext_vector_type(8))) short bf16x8;
typedef __attribute__((ext_vector_type(4))) float f32x4;

__device__ __forceinline__ unsigned short f2bf(float x) {
    unsigned u = __float_as_uint(x);
    u += 0x7FFFu + ((u >> 16) & 1u);
    return (unsigned short)(u >> 16);
}

__device__ __forceinline__ void glds16(const unsigned short* src, unsigned short* dst) {
    __builtin_amdgcn_global_load_lds(
        (const __attribute__((address_space(1))) void*)src,
        (__attribute__((address_space(3))) void*)dst, 16, 0, 0);
}

// ---- kernel 0: per-coefficient metadata (r, c, scales, dedup) ----
// 12 blocks x 64 threads (one wave each): block b owns p = b*64 + lane.
// Uniform 768-scan over an LDS copy -> broadcast reads, 12 CUs in parallel.
__global__ __launch_bounds__(64) void meta_kernel(
    const int* __restrict__ fidx, const float* __restrict__ dw,
    int* __restrict__ r_m, int* __restrict__ c_m,
    float* __restrict__ su_m, float* __restrict__ sv_m)
{
    __shared__ int idx_s[NCOEF];
    const int t = threadIdx.x;
    #pragma unroll
    for (int j = 0; j < 12; ++j) idx_s[t + j * 64] = fidx[t + j * 64];
    __syncthreads();
    const int p = blockIdx.x * 64 + t;
    const int idx = idx_s[p];
    // .at[].set semantics: last write wins -> kill earlier duplicates.
    int keep = 1;
    #pragma unroll 16
    for (int q = 0; q < NCOEF; ++q)
        keep &= (q <= p) | (idx_s[q] != idx);
    const int r = idx >> 12;          // / 4096
    const int c = idx & (NDIM - 1);   // % 4096
    const float s0 = 0.015625f;              // sqrt(1/4096)
    const float s1 = 0.022097086912079612f;  // sqrt(2/4096)
    r_m[p] = r;
    c_m[p] = c;
    su_m[p] = (r == 0) ? s0 : s1;
    sv_m[p] = (float)keep * ALPHA * dw[p] * ((c == 0) ? s0 : s1);
}

// ---- kernel 1: materialize U,V in PANEL layout ----
// U_p[((panel*96 + kc)*128 + row)*8 + pi]; i = panel*128+row, p = kc*8+pi.
// One block per (panel,kc): 2 KB contiguous per array. Integer-exact reduction.
__global__ __launch_bounds__(256) void fill_uv(
    const int* __restrict__ r_m, const int* __restrict__ c_m,
    const float* __restrict__ su_m, const float* __restrict__ sv_m,
    unsigned short* __restrict__ U, unsigned short* __restrict__ V)
{
    const int b = blockIdx.x;            // b = panel*96 + kc, 0..3071
    const int panel = b / 96;
    const int kc = b - panel * 96;
    const int t = threadIdx.x;
    const int row = (panel << 7) + (t >> 1);
    const int p0 = (kc << 3) + ((t & 1) << 2);
    const unsigned tt = 2u * (unsigned)row + 1u;
    const float w = 3.14159265358979323846f / 8192.0f;
    unsigned short uo[4], vo[4];
    #pragma unroll
    for (int j = 0; j < 4; ++j) {
        const int p = p0 + j;
        const unsigned nu = (tt * (unsigned)r_m[p]) & 16383u;
        const unsigned nv = (tt * (unsigned)c_m[p]) & 16383u;
        uo[j] = f2bf(su_m[p] * cosf((float)nu * w));
        vo[j] = f2bf(sv_m[p] * cosf((float)nv * w));
    }
    const size_t o = (size_t)b * 1024 + (size_t)t * 4;
    *(ushort4*)(U + o) = *(const ushort4*)uo;
    *(ushort4*)(V + o) = *(const ushort4*)vo;
}

// ---- kernel 2: out = W + U @ V^T  (M=N=4096, K=768) ----
// 128x128 tile, BK=32, 4 waves (2x2). FOUR LDS buffers, depth-2 prefetch,
// ONE barrier per K-step, counted vmcnt(8) (2 tiles in flight stay in
// flight). Stage target is 2-3 buffers ahead of any concurrent reader and
// single-barrier bounds wave skew to <1 iteration -> no overwrite hazard.
// MFMA operands swapped (mfma(b,a)): lane's 4 acc regs = 4 consecutive out
// columns -> float4 epilogue.
__global__ __launch_bounds__(256, 4) void gemm_kernel(
    const float* __restrict__ W,
    const unsigned short* __restrict__ U,
    const unsigned short* __restrict__ V,
    float* __restrict__ out)
{
    __shared__ unsigned short At[4 * 4096];  // [buf][chunk c=ks*128+row][8]
    __shared__ unsigned short Bt[4 * 4096];

    const int tid = threadIdx.x;
    const int lane = tid & 63;
    const int wave = tid >> 6;

    // XCD-aware swizzle: 1024 blocks, 8 XCDs, 128 contiguous per XCD
    const int bid = blockIdx.x;
    const int swz = (bid & 7) * 128 + (bid >> 3);
    const int by = swz >> 5;
    const int bx = swz & 31;
    const int brow = by * 128;
    const int bcol = bx * 128;
    const int wr = wave >> 1;
    const int wc = wave & 1;

    f32x4 acc[4][4] = {};

    const unsigned short* uPan = U + (size_t)by * 96 * 1024;
    const unsigned short* vPan = V + (size_t)bx * 96 * 1024;
    const size_t off0 = (size_t)tid * 8;
    const size_t off1 = (size_t)(256 + tid) * 8;
    const int wofs = wave << 9;   // wave-uniform LDS dest offset (u16)

    // fragment read: lane l, frag f -> row = w*64 + f*16 + (l&15), ks = l>>4
    const int fr = lane & 15;
    const int fks = lane >> 4;
    const int aRdO = (fks * 128 + wr * 64 + fr) << 3;
    const int bRdO = (fks * 128 + wc * 64 + fr) << 3;

#define STAGE(ks, buf) do {                                              \
        const unsigned short* uS = uPan + (size_t)(ks) * 4096;           \
        const unsigned short* vS = vPan + (size_t)(ks) * 4096;           \
        unsigned short* aD = At + (buf) * 4096;                          \
        unsigned short* bD = Bt + (buf) * 4096;                          \
        glds16(uS + off0, aD + wofs);                                    \
        glds16(uS + off1, aD + 2048 + wofs);                             \
        glds16(vS + off0, bD + wofs);                                    \
        glds16(vS + off1, bD + 2048 + wofs);                             \
    } while (0)

#define COMPUTE(buf) do {                                                \
        const unsigned short* aB = At + (buf) * 4096 + aRdO;             \
        const unsigned short* bB = Bt + (buf) * 4096 + bRdO;             \
        bf16x8 a[4], b[4];                                               \
        _Pragma("unroll")                                                \
        for (int f = 0; f < 4; ++f) {                                    \
            a[f] = *(const bf16x8*)(aB + (f << 7));                      \
            b[f] = *(const bf16x8*)(bB + (f << 7));                      \
        }                                                                \
        _Pragma("unroll")                                                \
        for (int fm = 0; fm < 4; ++fm)                                   \
            _Pragma("unroll")                                            \
            for (int fn = 0; fn < 4; ++fn)                               \
                acc[fm][fn] = __builtin_amdgcn_mfma_f32_16x16x32_bf16(   \
                    b[fn], a[fm], acc[fm][fn], 0, 0, 0);                 \
    } while (0)

    STAGE(0, 0);
    STAGE(1, 1);
    #pragma unroll
    for (int i = 0; i < 24; ++i) {
        if (i < 22) {
            STAGE(i + 2, (i + 2) & 3);
            asm volatile("s_waitcnt vmcnt(8)" ::: "memory");
        } else if (i == 22) {
            asm volatile("s_waitcnt vmcnt(4)" ::: "memory");
        } else {
            asm volatile("s_waitcnt vmcnt(0)" ::: "memory");
        }
        __builtin_amdgcn_s_barrier();
        asm volatile("" ::: "memory");
        COMPUTE(i & 3);
    }

    // epilogue: out = W + acc (alpha folded into V). Swapped-operand C/D
    // layout: lane holds row = lane&15 (fixed), cols = (lane>>4)*4 .. +3.
    const int erow = brow + wr * 64 + fr;
    const int ecol = bcol + wc * 64 + ((lane >> 4) << 2);
    #pragma unroll
    for (int fm = 0; fm < 4; ++fm) {
        #pragma unroll
        for (int fn = 0; fn < 4; ++fn) {
            const size_t o = (size_t)(erow + fm * 16) * NDIM + (ecol + fn * 16);
            const float4 w4 = *(const float4*)(W + o);
            float4 r4;
            r4.x = w4.x + acc[fm][fn][0];
            r4.y = w4.y + acc[fm][fn][1];
            r4.z = w4.z + acc[fm][fn][2];
            r4.w = w4.w + acc[fm][fn][3];
            *(float4*)(out + o) = r4;
        }
    }
#undef STAGE
#undef COMPUTE
}

extern "C" void kernel_launch(void* const* d_in, const int* in_sizes, int n_in,
                              void* d_out, int out_size, void* d_ws, size_t ws_size,
                              hipStream_t stream) {
    const float* weight = (const float*)d_in[0];
    const float* dw     = (const float*)d_in[1];
    const int*   fidx   = (const int*)d_in[2];
    float* out = (float*)d_out;

    char* ws = (char*)d_ws;
    unsigned short* U = (unsigned short*)ws;                       // 6,291,456 B
    unsigned short* V = (unsigned short*)(ws + 6291456);           // 6,291,456 B
    char* meta = ws + 2 * 6291456;
    int*   r_m  = (int*)(meta);
    int*   c_m  = (int*)(meta + NCOEF * 4);
    float* su_m = (float*)(meta + NCOEF * 8);
    float* sv_m = (float*)(meta + NCOEF * 12);

    meta_kernel<<<12, 64, 0, stream>>>(fidx, dw, r_m, c_m, su_m, sv_m);
    fill_uv<<<32 * 96, 256, 0, stream>>>(r_m, c_m, su_m, sv_m, U, V);
    gemm_kernel<<<1024, 256, 0, stream>>>(weight, U, V, out);
}